// Round 7
// baseline (173.682 us; speedup 1.0000x reference)
//
#include <hip/hip_runtime.h>
#include <hip/hip_bf16.h>
#include <stdint.h>
#include <stddef.h>

#define N_    4096
#define C_    1000
#define CP    1024
#define A_    64
#define KPACK 2080            // 64*65/2 packed upper-triangular
#define KCROSS (KPACK + 64)   // 2144 (end of live data)
#define KTOT  2176            // row length in fp8 bytes (17 x 128)
#define KSPLIT 1152           // z-slice boundary: 9 + 8 iterations of BK=128
#define MS    68              // LDS row stride for M staging (16B-aligned)
#define YPER  8000            // floats of y copied per gemm block (512 blocks)

typedef __bf16 bf16_8 __attribute__((ext_vector_type(8)));
typedef float  f32_4  __attribute__((ext_vector_type(4)));

__device__ __forceinline__ void gl2lds16(const void* g, void* l) {
  __builtin_amdgcn_global_load_lds(
      (const __attribute__((address_space(1))) void*)g,
      (__attribute__((address_space(3))) void*)l, 16, 0, 0);
}

// pack two floats -> two OCP e4m3 bytes (low 16 bits)
__device__ __forceinline__ uint16_t pk_fp8(float a, float b) {
  return (uint16_t)(__builtin_amdgcn_cvt_pk_fp8_f32(a, b, 0, false) & 0xffff);
}

// unpack packed upper-tri index k -> (a,b), a<=b.  off(a)=a*(129-a)/2
__device__ __forceinline__ void unpack_pair(int k, int& a, int& b) {
  a = (int)(0.5f * (129.0f - sqrtf((float)(16641 - 8 * k))));
  if (a < 0) a = 0;
  while ((a + 1) * (129 - (a + 1)) / 2 <= k) ++a;
  while (a * (129 - a) / 2 > k) --a;
  b = k - a * (129 - a) / 2 + a;
}

// ---------------- prep_all: blocks [0,1024) -> Bo + w2; [1024,5120) -> Aq + qn
__global__ __launch_bounds__(256) void prep_all(
    const float* __restrict__ W, const int* __restrict__ tgt,
    const float* __restrict__ CV, uint8_t* __restrict__ Bo,
    float* __restrict__ w2, uint8_t* __restrict__ Aq, float* __restrict__ qn) {
  __shared__ float Ms[64 * MS];
  __shared__ float up[4 * 64];
  __shared__ float wk[64];
  __shared__ float us[64];
  int t = threadIdx.x;

  if (blockIdx.x < 1024) {
    int c = blockIdx.x;
    float* ws = Ms;
    if (t < 64) {
      float w = (c < C_) ? W[c * 64 + t] : 0.f;
      ws[t] = w;
      float s = w * w;
      for (int o = 32; o; o >>= 1) s += __shfl_down(s, o);
      if (t == 0 && c < C_) w2[c] = s;
    }
    __syncthreads();
    uint8_t* row = Bo + (size_t)c * KTOT;
    for (int p = t; p < KPACK / 2; p += 256) {
      int k = 2 * p;
      int a0, b0, a1, b1;
      unpack_pair(k, a0, b0);
      if (b0 == 63) { a1 = a0 + 1; b1 = a1; } else { a1 = a0; b1 = b0 + 1; }
      *(uint16_t*)(row + k) = pk_fp8(ws[a0] * ws[b0], ws[a1] * ws[b1]);
    }
    if (t < 32) *(uint16_t*)(row + KPACK + 2 * t) = pk_fp8(ws[2 * t], ws[2 * t + 1]);
    if (t >= 32 && t < 48) *(uint16_t*)(row + KCROSS + 2 * (t - 32)) = 0;
  } else {
    int n = blockIdx.x - 1024;
    int lbl = tgt[n];
    if (t < 64) wk[t] = W[lbl * 64 + t];
    const float4* M4 = (const float4*)(CV + (size_t)n * 4096);
    for (int j = 0; j < 4; ++j) {
      int i4 = t + j * 256;
      int r = i4 >> 4, c4 = (i4 & 15) << 2;
      *(float4*)&Ms[r * MS + c4] = M4[i4];
    }
    __syncthreads();
    {
      int a = t & 63, seg = t >> 6;
      float acc = 0.f;
      for (int b = seg * 16; b < seg * 16 + 16; ++b)
        acc += (Ms[a * MS + b] + Ms[b * MS + a]) * wk[b];
      up[seg * 64 + a] = acc;
    }
    __syncthreads();
    if (t < 64) {
      float u = up[t] + up[64 + t] + up[128 + t] + up[192 + t];
      us[t] = u;
      float p = wk[t] * u;
      for (int o = 32; o; o >>= 1) p += __shfl_down(p, o);
      if (t == 0) qn[n] = 0.5f * p;
    }
    __syncthreads();
    uint8_t* row = Aq + (size_t)n * KTOT;
    for (int p = t; p < KPACK / 2; p += 256) {
      int k = 2 * p;
      int a0, b0, a1, b1;
      unpack_pair(k, a0, b0);
      if (b0 == 63) { a1 = a0 + 1; b1 = a1; } else { a1 = a0; b1 = b0 + 1; }
      float v0 = (a0 == b0) ? Ms[a0 * MS + a0] : (Ms[a0 * MS + b0] + Ms[b0 * MS + a0]);
      float v1 = (a1 == b1) ? Ms[a1 * MS + a1] : (Ms[a1 * MS + b1] + Ms[b1 * MS + a1]);
      *(uint16_t*)(row + k) = pk_fp8(v0, v1);
    }
    if (t < 32) *(uint16_t*)(row + KPACK + 2 * t) = pk_fp8(-us[2 * t], -us[2 * t + 1]);
    if (t >= 32 && t < 48) *(uint16_t*)(row + KCROSS + 2 * (t - 32)) = 0;
  }
}

// ---------------- GEMM (fp8): S_z[n,c] = sum_{k in slice z} Aq[n,k]*Bo[c,k] ---
// BM=BN=128, BK=128 fp8. z=2 uneven split (9/8 iters). Grid = (32 rows FAST,
// 8 cols, 2 z) for XCD pinning. XOR 16B-chunk swizzle on LDS.
// MFMA operands SWAPPED (bf, af): D row = c index, D col = n index ->
// each acc group packs to one 8B store in row-major S.
// Each block also copies YPER floats of y -> outy, hidden in the K loop.
#define BM 128
#define BN 128
#define BK 128
__global__ __launch_bounds__(256) void gemm_s(const uint8_t* __restrict__ Aq,
                                              const uint8_t* __restrict__ Bo,
                                              __bf16* __restrict__ Sbase,
                                              const float* __restrict__ y,
                                              float* __restrict__ outy) {
  __shared__ uint8_t As[BM * BK];   // 16 KB
  __shared__ uint8_t Bs[BN * BK];   // 16 KB
  int t = threadIdx.x;
  int lane = t & 63;
  int w = t >> 6;
  int wr = w & 1;
  int wc = w >> 1;
  int rowBase = blockIdx.x * BM;   // row index FASTEST for XCD pinning
  int colBase = blockIdx.y * BN;
  int kb = blockIdx.z ? KSPLIT : 0;
  int ke = blockIdx.z ? KTOT : KSPLIT;
  __bf16* S = Sbase + (size_t)blockIdx.z * ((size_t)N_ * CP);

  // y-passthrough slice for this block
  int bid = blockIdx.x + 32 * blockIdx.y + 256 * blockIdx.z;   // 0..511
  const float* ysrc = y + (size_t)bid * YPER;
  float* ydst = outy + (size_t)bid * YPER;

  f32_4 acc[4][4];
  for (int mi = 0; mi < 4; ++mi)
    for (int ni = 0; ni < 4; ++ni)
      acc[mi][ni] = (f32_4){0.f, 0.f, 0.f, 0.f};

  int m0 = lane & 15;
  int q = lane >> 4;           // K-quarter within MFMA
  int sw = m0 & 7;             // swizzle key (row&7 == m0&7 for compute rows)

  int it = 0;
  for (int k0 = kb; k0 < ke; k0 += BK) {
    __syncthreads();
    for (int r = 0; r < 4; ++r) {
      int ch = r * 256 + t;
      int row_p = ch >> 3, qp = ch & 7;
      int q_log = qp ^ (row_p & 7);
      const uint8_t* g = Aq + (size_t)(rowBase + row_p) * KTOT + k0 + (q_log << 4);
      gl2lds16(g, As + ch * 16);
    }
    for (int r = 0; r < 4; ++r) {
      int ch = r * 256 + t;
      int row_p = ch >> 3, qp = ch & 7;
      int q_log = qp ^ (row_p & 7);
      const uint8_t* g = Bo + (size_t)(colBase + row_p) * KTOT + k0 + (q_log << 4);
      gl2lds16(g, Bs + ch * 16);
    }
    // y-copy chunk: drains at the same barrier the staging loads need anyway
    {
      int base = it * 1000;
      ++it;
      for (int i = base + t; i < base + 1000 && i < YPER; i += 256)
        ydst[i] = ysrc[i];
    }
    __syncthreads();
    for (int s = 0; s < 4; ++s) {          // 4 x K=32 MFMA steps per BK=128
      int c_log = 2 * s + (q >> 1);        // logical 16B chunk of this lane's 8B
      int off = ((c_log ^ sw) << 4) + ((q & 1) << 3);
      long af[4], bf[4];
      for (int mi = 0; mi < 4; ++mi)
        af[mi] = *(const long*)&As[(wr * 64 + mi * 16 + m0) * BK + off];
      for (int ni = 0; ni < 4; ++ni)
        bf[ni] = *(const long*)&Bs[(wc * 64 + ni * 16 + m0) * BK + off];
      for (int mi = 0; mi < 4; ++mi)
        for (int ni = 0; ni < 4; ++ni)
          acc[mi][ni] = __builtin_amdgcn_mfma_f32_16x16x32_fp8_fp8(
              bf[ni], af[mi], acc[mi][ni], 0, 0, 0);   // SWAPPED operands
    }
  }

  // Swapped-D layout: row(=c) = (lane>>4)*4 + reg, col(=n) = lane&15.
  // acc[mi][ni] regs j=0..3 are c0..c0+3 in row n0 -> one 8B packed store.
  int ll = lane & 15;          // n offset
  int lh = lane >> 4;          // c quad
  for (int mi = 0; mi < 4; ++mi) {
    int n0 = rowBase + wr * 64 + mi * 16 + ll;
    for (int ni = 0; ni < 4; ++ni) {
      int c0 = colBase + wc * 64 + ni * 16 + lh * 4;
      union { __bf16 h[4]; uint2 u; } pk;
      for (int j = 0; j < 4; ++j) pk.h[j] = (__bf16)acc[mi][ni][j];
      *(uint2*)&S[(size_t)n0 * CP + c0] = pk.u;
    }
  }
}

// ---------------- epilogue: wave-per-row softmax -> nll[n] ----------------
__global__ __launch_bounds__(256) void epilogue(
    const __bf16* __restrict__ Sb, const float* __restrict__ y,
    const float* __restrict__ w2, const float* __restrict__ qn,
    const int* __restrict__ tgt, const float* __restrict__ ratio_p,
    float* __restrict__ nll) {
  int t = threadIdx.x, lane = t & 63, w = t >> 6;
  int n = blockIdx.x * 4 + w;
  float hr = 0.5f * (*ratio_p);
  int lbl = tgt[n];
  float q = qn[n];
  float w2k = w2[lbl];
  const bf16_8* S0 = (const bf16_8*)(Sb + (size_t)n * CP);
  const bf16_8* S1 = (const bf16_8*)(Sb + 1ull * N_ * CP + (size_t)n * CP);
  const float* yr = y + (size_t)n * C_;
  float l[16];
  float mx = -1e30f;
  for (int i = 0; i < 2; ++i) {
    int idx = i * 64 + lane;             // bf16_8 index; c = idx*8+j
    bf16_8 a0 = S0[idx], a1 = S1[idx];
    int c0 = idx * 8;
    for (int j = 0; j < 8; ++j) {
      int c = c0 + j;
      float v = -1e30f;
      if (c < C_) {
        float s = (float)a0[j] + (float)a1[j];
        v = yr[c] + (w2[c] - w2k) + hr * (s + q);
      }
      l[i * 8 + j] = v;
      mx = fmaxf(mx, v);
    }
  }
  for (int o = 32; o; o >>= 1) mx = fmaxf(mx, __shfl_xor(mx, o));
  float se = 0.f, lt = 0.f;
  for (int i = 0; i < 2; ++i) {
    int c0 = (i * 64 + lane) * 8;
    for (int j = 0; j < 8; ++j) {
      float v = l[i * 8 + j];
      se += expf(v - mx);               // -1e30 lanes contribute exactly 0
      lt += (c0 + j == lbl) ? v : 0.f;
    }
  }
  for (int o = 32; o; o >>= 1) {
    se += __shfl_xor(se, o);
    lt += __shfl_xor(lt, o);
  }
  if (lane == 0) nll[n] = (mx + logf(se)) - lt;
}

// ---------------- final mean (single block, no atomics) ----------------
__global__ void reduce_loss(const float* __restrict__ nll, float* __restrict__ out) {
  int t = threadIdx.x;  // 256
  float s = 0.f;
  for (int i = t; i < N_; i += 256) s += nll[i];
  for (int o = 32; o; o >>= 1) s += __shfl_down(s, o);
  __shared__ float r[4];
  if ((t & 63) == 0) r[t >> 6] = s;
  __syncthreads();
  if (t == 0) out[0] = (r[0] + r[1] + r[2] + r[3]) * (1.0f / (float)N_);
}

extern "C" void kernel_launch(void* const* d_in, const int* in_sizes, int n_in,
                              void* d_out, int out_size, void* d_ws, size_t ws_size,
                              hipStream_t stream) {
  const float* W     = (const float*)d_in[0];   // (C, A)
  const float* y     = (const float*)d_in[1];   // (N, C)
  const int*   tgt   = (const int*)d_in[3];     // (N,)
  const float* ratio = (const float*)d_in[4];   // scalar
  const float* CV    = (const float*)d_in[5];   // (N, A, A)

  char* ws = (char*)d_ws;
  size_t off = 0;
  uint8_t* Aq = (uint8_t*)(ws + off); off += (size_t)N_ * KTOT;
  uint8_t* Bo = (uint8_t*)(ws + off); off += (size_t)CP * KTOT;
  __bf16* S   = (__bf16*)(ws + off);  off += 2ull * N_ * CP * sizeof(__bf16);
  float* w2   = (float*)(ws + off);   off += 4096;
  float* qn   = (float*)(ws + off);   off += (size_t)N_ * sizeof(float);
  float* nll  = (float*)(ws + off);   off += (size_t)N_ * sizeof(float);

  float* out = (float*)d_out;

  prep_all<<<1024 + N_, 256, 0, stream>>>(W, tgt, CV, Bo, w2, Aq, qn);
  gemm_s<<<dim3(N_ / BM, CP / BN, 2), 256, 0, stream>>>(Aq, Bo, S, y, out + 1);
  epilogue<<<N_ / 4, 256, 0, stream>>>(S, y, w2, qn, tgt, ratio, nll);
  reduce_loss<<<1, 256, 0, stream>>>(nll, out);
}

// Round 8
// 165.499 us; speedup vs baseline: 1.0494x; 1.0494x over previous
//
#include <hip/hip_runtime.h>
#include <hip/hip_bf16.h>
#include <stdint.h>
#include <stddef.h>

#define N_    4096
#define C_    1000
#define CP    1024
#define A_    64
#define KPACK 2080            // 64*65/2 packed upper-triangular
#define KCROSS (KPACK + 64)   // 2144 (end of live data)
#define KTOT  2176            // row length in fp8 bytes (17 x 128)
#define KSPLIT 1152           // z-slice boundary: 9 + 8 iterations of BK=128
#define MS    68              // LDS row stride for M staging (16B-aligned)

typedef __bf16 bf16_8 __attribute__((ext_vector_type(8)));
typedef float  f32_4  __attribute__((ext_vector_type(4)));

__device__ __forceinline__ void gl2lds16(const void* g, void* l) {
  __builtin_amdgcn_global_load_lds(
      (const __attribute__((address_space(1))) void*)g,
      (__attribute__((address_space(3))) void*)l, 16, 0, 0);
}

// pack two floats -> two OCP e4m3 bytes (low 16 bits)
__device__ __forceinline__ uint16_t pk_fp8(float a, float b) {
  return (uint16_t)(__builtin_amdgcn_cvt_pk_fp8_f32(a, b, 0, false) & 0xffff);
}

// unpack packed upper-tri index k -> (a,b), a<=b.  off(a)=a*(129-a)/2
__device__ __forceinline__ void unpack_pair(int k, int& a, int& b) {
  a = (int)(0.5f * (129.0f - sqrtf((float)(16641 - 8 * k))));
  if (a < 0) a = 0;
  while ((a + 1) * (129 - (a + 1)) / 2 <= k) ++a;
  while (a * (129 - a) / 2 > k) --a;
  b = k - a * (129 - a) / 2 + a;
}

// ---------------- prep_all: blocks [0,1024) -> Bo + w2; [1024,5120) -> Aq + qn
__global__ __launch_bounds__(256) void prep_all(
    const float* __restrict__ W, const int* __restrict__ tgt,
    const float* __restrict__ CV, uint8_t* __restrict__ Bo,
    float* __restrict__ w2, uint8_t* __restrict__ Aq, float* __restrict__ qn) {
  __shared__ float Ms[64 * MS];
  __shared__ float up[4 * 64];
  __shared__ float wk[64];
  __shared__ float us[64];
  int t = threadIdx.x;

  if (blockIdx.x < 1024) {
    int c = blockIdx.x;
    float* ws = Ms;
    if (t < 64) {
      float w = (c < C_) ? W[c * 64 + t] : 0.f;
      ws[t] = w;
      float s = w * w;
      for (int o = 32; o; o >>= 1) s += __shfl_down(s, o);
      if (t == 0 && c < C_) w2[c] = s;
    }
    __syncthreads();
    uint8_t* row = Bo + (size_t)c * KTOT;
    for (int p = t; p < KPACK / 2; p += 256) {
      int k = 2 * p;
      int a0, b0, a1, b1;
      unpack_pair(k, a0, b0);
      if (b0 == 63) { a1 = a0 + 1; b1 = a1; } else { a1 = a0; b1 = b0 + 1; }
      *(uint16_t*)(row + k) = pk_fp8(ws[a0] * ws[b0], ws[a1] * ws[b1]);
    }
    if (t < 32) *(uint16_t*)(row + KPACK + 2 * t) = pk_fp8(ws[2 * t], ws[2 * t + 1]);
    if (t >= 32 && t < 48) *(uint16_t*)(row + KCROSS + 2 * (t - 32)) = 0;
  } else {
    int n = blockIdx.x - 1024;
    int lbl = tgt[n];
    if (t < 64) wk[t] = W[lbl * 64 + t];
    const float4* M4 = (const float4*)(CV + (size_t)n * 4096);
    for (int j = 0; j < 4; ++j) {
      int i4 = t + j * 256;
      int r = i4 >> 4, c4 = (i4 & 15) << 2;
      *(float4*)&Ms[r * MS + c4] = M4[i4];
    }
    __syncthreads();
    {
      int a = t & 63, seg = t >> 6;
      float acc = 0.f;
      for (int b = seg * 16; b < seg * 16 + 16; ++b)
        acc += (Ms[a * MS + b] + Ms[b * MS + a]) * wk[b];
      up[seg * 64 + a] = acc;
    }
    __syncthreads();
    if (t < 64) {
      float u = up[t] + up[64 + t] + up[128 + t] + up[192 + t];
      us[t] = u;
      float p = wk[t] * u;
      for (int o = 32; o; o >>= 1) p += __shfl_down(p, o);
      if (t == 0) qn[n] = 0.5f * p;
    }
    __syncthreads();
    uint8_t* row = Aq + (size_t)n * KTOT;
    for (int p = t; p < KPACK / 2; p += 256) {
      int k = 2 * p;
      int a0, b0, a1, b1;
      unpack_pair(k, a0, b0);
      if (b0 == 63) { a1 = a0 + 1; b1 = a1; } else { a1 = a0; b1 = b0 + 1; }
      float v0 = (a0 == b0) ? Ms[a0 * MS + a0] : (Ms[a0 * MS + b0] + Ms[b0 * MS + a0]);
      float v1 = (a1 == b1) ? Ms[a1 * MS + a1] : (Ms[a1 * MS + b1] + Ms[b1 * MS + a1]);
      *(uint16_t*)(row + k) = pk_fp8(v0, v1);
    }
    if (t < 32) *(uint16_t*)(row + KPACK + 2 * t) = pk_fp8(-us[2 * t], -us[2 * t + 1]);
    if (t >= 32 && t < 48) *(uint16_t*)(row + KCROSS + 2 * (t - 32)) = 0;
  }
}

// ---------------- GEMM (fp8): S_z[n,c] = sum_{k in slice z} Aq[n,k]*Bo[c,k] ---
// BM=BN=128, BK=128 fp8. z=2 uneven split (9/8 iters). Grid = (32 rows FAST,
// 8 cols, 2 z) for XCD pinning. XOR 16B-chunk swizzle on LDS.
// MFMA operands SWAPPED (bf, af): D row = c index, D col = n index ->
// each acc group packs to one 8B store in row-major S.
#define BM 128
#define BN 128
#define BK 128
__global__ __launch_bounds__(256) void gemm_s(const uint8_t* __restrict__ Aq,
                                              const uint8_t* __restrict__ Bo,
                                              __bf16* __restrict__ Sbase) {
  __shared__ uint8_t As[BM * BK];   // 16 KB
  __shared__ uint8_t Bs[BN * BK];   // 16 KB
  int t = threadIdx.x;
  int lane = t & 63;
  int w = t >> 6;
  int wr = w & 1;
  int wc = w >> 1;
  int rowBase = blockIdx.x * BM;   // row index FASTEST for XCD pinning
  int colBase = blockIdx.y * BN;
  int kb = blockIdx.z ? KSPLIT : 0;
  int ke = blockIdx.z ? KTOT : KSPLIT;
  __bf16* S = Sbase + (size_t)blockIdx.z * ((size_t)N_ * CP);

  f32_4 acc[4][4];
  for (int mi = 0; mi < 4; ++mi)
    for (int ni = 0; ni < 4; ++ni)
      acc[mi][ni] = (f32_4){0.f, 0.f, 0.f, 0.f};

  int m0 = lane & 15;
  int q = lane >> 4;           // K-quarter within MFMA
  int sw = m0 & 7;             // swizzle key (row&7 == m0&7 for compute rows)

  for (int k0 = kb; k0 < ke; k0 += BK) {
    __syncthreads();
    for (int r = 0; r < 4; ++r) {
      int ch = r * 256 + t;
      int row_p = ch >> 3, qp = ch & 7;
      int q_log = qp ^ (row_p & 7);
      const uint8_t* g = Aq + (size_t)(rowBase + row_p) * KTOT + k0 + (q_log << 4);
      gl2lds16(g, As + ch * 16);
    }
    for (int r = 0; r < 4; ++r) {
      int ch = r * 256 + t;
      int row_p = ch >> 3, qp = ch & 7;
      int q_log = qp ^ (row_p & 7);
      const uint8_t* g = Bo + (size_t)(colBase + row_p) * KTOT + k0 + (q_log << 4);
      gl2lds16(g, Bs + ch * 16);
    }
    __syncthreads();
    for (int s = 0; s < 4; ++s) {          // 4 x K=32 MFMA steps per BK=128
      int c_log = 2 * s + (q >> 1);        // logical 16B chunk of this lane's 8B
      int off = ((c_log ^ sw) << 4) + ((q & 1) << 3);
      long af[4], bf[4];
      for (int mi = 0; mi < 4; ++mi)
        af[mi] = *(const long*)&As[(wr * 64 + mi * 16 + m0) * BK + off];
      for (int ni = 0; ni < 4; ++ni)
        bf[ni] = *(const long*)&Bs[(wc * 64 + ni * 16 + m0) * BK + off];
      for (int mi = 0; mi < 4; ++mi)
        for (int ni = 0; ni < 4; ++ni)
          acc[mi][ni] = __builtin_amdgcn_mfma_f32_16x16x32_fp8_fp8(
              bf[ni], af[mi], acc[mi][ni], 0, 0, 0);   // SWAPPED operands
    }
  }

  // Swapped-D layout: row(=c) = (lane>>4)*4 + reg, col(=n) = lane&15.
  // acc[mi][ni] regs j=0..3 are c0..c0+3 in row n0 -> one 8B packed store.
  int ll = lane & 15;          // n offset
  int lh = lane >> 4;          // c quad
  for (int mi = 0; mi < 4; ++mi) {
    int n0 = rowBase + wr * 64 + mi * 16 + ll;
    for (int ni = 0; ni < 4; ++ni) {
      int c0 = colBase + wc * 64 + ni * 16 + lh * 4;
      union { __bf16 h[4]; uint2 u; } pk;
      for (int j = 0; j < 4; ++j) pk.h[j] = (__bf16)acc[mi][ni][j];
      *(uint2*)&S[(size_t)n0 * CP + c0] = pk.u;
    }
  }
}

// ---------------- epilogue: wave-per-row softmax + y passthrough ----------------
__global__ __launch_bounds__(256) void epilogue(
    const __bf16* __restrict__ Sb, const float* __restrict__ y,
    const float* __restrict__ w2, const float* __restrict__ qn,
    const int* __restrict__ tgt, const float* __restrict__ ratio_p,
    float* __restrict__ nll, float* __restrict__ outy) {
  int t = threadIdx.x, lane = t & 63, w = t >> 6;
  int n = blockIdx.x * 4 + w;
  float hr = 0.5f * (*ratio_p);
  int lbl = tgt[n];
  float q = qn[n];
  float w2k = w2[lbl];
  const bf16_8* S0 = (const bf16_8*)(Sb + (size_t)n * CP);
  const bf16_8* S1 = (const bf16_8*)(Sb + 1ull * N_ * CP + (size_t)n * CP);
  const float* yr = y + (size_t)n * C_;
  float* oy = outy + (size_t)n * C_;
  float l[16];
  float mx = -1e30f;
  for (int i = 0; i < 2; ++i) {
    int idx = i * 64 + lane;             // bf16_8 index; c = idx*8+j
    bf16_8 a0 = S0[idx], a1 = S1[idx];
    int c0 = idx * 8;
    for (int j = 0; j < 8; ++j) {
      int c = c0 + j;
      float v = -1e30f;
      if (c < C_) {
        float s = (float)a0[j] + (float)a1[j];
        v = yr[c] + (w2[c] - w2k) + hr * (s + q);
      }
      l[i * 8 + j] = v;
      mx = fmaxf(mx, v);
    }
  }
  // y passthrough (out+1 is only 4B-aligned -> scalar coalesced copy)
  for (int c = lane; c < C_; c += 64) oy[c] = yr[c];
  for (int o = 32; o; o >>= 1) mx = fmaxf(mx, __shfl_xor(mx, o));
  float se = 0.f, lt = 0.f;
  for (int i = 0; i < 2; ++i) {
    int c0 = (i * 64 + lane) * 8;
    for (int j = 0; j < 8; ++j) {
      float v = l[i * 8 + j];
      se += expf(v - mx);               // -1e30 lanes contribute exactly 0
      lt += (c0 + j == lbl) ? v : 0.f;
    }
  }
  for (int o = 32; o; o >>= 1) {
    se += __shfl_xor(se, o);
    lt += __shfl_xor(lt, o);
  }
  if (lane == 0) nll[n] = (mx + logf(se)) - lt;
}

// ---------------- final mean (single block, no atomics) ----------------
__global__ void reduce_loss(const float* __restrict__ nll, float* __restrict__ out) {
  int t = threadIdx.x;  // 256
  float s = 0.f;
  for (int i = t; i < N_; i += 256) s += nll[i];
  for (int o = 32; o; o >>= 1) s += __shfl_down(s, o);
  __shared__ float r[4];
  if ((t & 63) == 0) r[t >> 6] = s;
  __syncthreads();
  if (t == 0) out[0] = (r[0] + r[1] + r[2] + r[3]) * (1.0f / (float)N_);
}

extern "C" void kernel_launch(void* const* d_in, const int* in_sizes, int n_in,
                              void* d_out, int out_size, void* d_ws, size_t ws_size,
                              hipStream_t stream) {
  const float* W     = (const float*)d_in[0];   // (C, A)
  const float* y     = (const float*)d_in[1];   // (N, C)
  const int*   tgt   = (const int*)d_in[3];     // (N,)
  const float* ratio = (const float*)d_in[4];   // scalar
  const float* CV    = (const float*)d_in[5];   // (N, A, A)

  char* ws = (char*)d_ws;
  size_t off = 0;
  uint8_t* Aq = (uint8_t*)(ws + off); off += (size_t)N_ * KTOT;
  uint8_t* Bo = (uint8_t*)(ws + off); off += (size_t)CP * KTOT;
  __bf16* S   = (__bf16*)(ws + off);  off += 2ull * N_ * CP * sizeof(__bf16);
  float* w2   = (float*)(ws + off);   off += 4096;
  float* qn   = (float*)(ws + off);   off += (size_t)N_ * sizeof(float);
  float* nll  = (float*)(ws + off);   off += (size_t)N_ * sizeof(float);

  float* out = (float*)d_out;

  prep_all<<<1024 + N_, 256, 0, stream>>>(W, tgt, CV, Bo, w2, Aq, qn);
  gemm_s<<<dim3(N_ / BM, CP / BN, 2), 256, 0, stream>>>(Aq, Bo, S);
  epilogue<<<N_ / 4, 256, 0, stream>>>(S, y, w2, qn, tgt, ratio, nll, out + 1);
  reduce_loss<<<1, 256, 0, stream>>>(nll, out);
}

// Round 9
// 165.421 us; speedup vs baseline: 1.0499x; 1.0005x over previous
//
#include <hip/hip_runtime.h>
#include <hip/hip_bf16.h>
#include <stdint.h>
#include <stddef.h>

#define N_    4096
#define C_    1000
#define CP    1024
#define A_    64
#define KPACK 2080            // 64*65/2 packed upper-triangular
#define KCROSS (KPACK + 64)   // 2144 (end of live data)
#define KTOT  2176            // row length in fp8 bytes (17 x 128)
#define KSPLIT 1152           // z-slice boundary: 9 + 8 iterations of BK=128
#define MS    68              // LDS row stride for M staging (16B-aligned)

typedef __bf16 bf16_8 __attribute__((ext_vector_type(8)));
typedef float  f32_4  __attribute__((ext_vector_type(4)));

__device__ __forceinline__ void gl2lds16(const void* g, void* l) {
  __builtin_amdgcn_global_load_lds(
      (const __attribute__((address_space(1))) void*)g,
      (__attribute__((address_space(3))) void*)l, 16, 0, 0);
}

// pack two floats -> two OCP e4m3 bytes (low 16 bits)
__device__ __forceinline__ uint16_t pk_fp8(float a, float b) {
  return (uint16_t)(__builtin_amdgcn_cvt_pk_fp8_f32(a, b, 0, false) & 0xffff);
}

// unpack packed upper-tri index k -> (a,b), a<=b.  off(a)=a*(129-a)/2
__device__ __forceinline__ void unpack_pair(int k, int& a, int& b) {
  a = (int)(0.5f * (129.0f - sqrtf((float)(16641 - 8 * k))));
  if (a < 0) a = 0;
  while ((a + 1) * (129 - (a + 1)) / 2 <= k) ++a;
  while (a * (129 - a) / 2 > k) --a;
  b = k - a * (129 - a) / 2 + a;
}

// ---------------- prep_all: blocks [0,1024) -> Bo + w2; [1024,5120) -> Aq + qn
__global__ __launch_bounds__(256) void prep_all(
    const float* __restrict__ W, const int* __restrict__ tgt,
    const float* __restrict__ CV, uint8_t* __restrict__ Bo,
    float* __restrict__ w2, uint8_t* __restrict__ Aq, float* __restrict__ qn) {
  __shared__ float Ms[64 * MS];
  __shared__ float up[4 * 64];
  __shared__ float wk[64];
  __shared__ float us[64];
  int t = threadIdx.x;

  if (blockIdx.x < 1024) {
    int c = blockIdx.x;
    float* ws = Ms;
    if (t < 64) {
      float w = (c < C_) ? W[c * 64 + t] : 0.f;
      ws[t] = w;
      float s = w * w;
      for (int o = 32; o; o >>= 1) s += __shfl_down(s, o);
      if (t == 0 && c < C_) w2[c] = s;
    }
    __syncthreads();
    uint8_t* row = Bo + (size_t)c * KTOT;
    for (int p = t; p < KPACK / 2; p += 256) {
      int k = 2 * p;
      int a0, b0, a1, b1;
      unpack_pair(k, a0, b0);
      if (b0 == 63) { a1 = a0 + 1; b1 = a1; } else { a1 = a0; b1 = b0 + 1; }
      *(uint16_t*)(row + k) = pk_fp8(ws[a0] * ws[b0], ws[a1] * ws[b1]);
    }
    if (t < 32) *(uint16_t*)(row + KPACK + 2 * t) = pk_fp8(ws[2 * t], ws[2 * t + 1]);
    if (t >= 32 && t < 48) *(uint16_t*)(row + KCROSS + 2 * (t - 32)) = 0;
  } else {
    int n = blockIdx.x - 1024;
    int lbl = tgt[n];
    if (t < 64) wk[t] = W[lbl * 64 + t];
    const float4* M4 = (const float4*)(CV + (size_t)n * 4096);
    for (int j = 0; j < 4; ++j) {
      int i4 = t + j * 256;
      int r = i4 >> 4, c4 = (i4 & 15) << 2;
      *(float4*)&Ms[r * MS + c4] = M4[i4];
    }
    __syncthreads();
    {
      int a = t & 63, seg = t >> 6;
      float acc = 0.f;
      for (int b = seg * 16; b < seg * 16 + 16; ++b)
        acc += (Ms[a * MS + b] + Ms[b * MS + a]) * wk[b];
      up[seg * 64 + a] = acc;
    }
    __syncthreads();
    if (t < 64) {
      float u = up[t] + up[64 + t] + up[128 + t] + up[192 + t];
      us[t] = u;
      float p = wk[t] * u;
      for (int o = 32; o; o >>= 1) p += __shfl_down(p, o);
      if (t == 0) qn[n] = 0.5f * p;
    }
    __syncthreads();
    uint8_t* row = Aq + (size_t)n * KTOT;
    for (int p = t; p < KPACK / 2; p += 256) {
      int k = 2 * p;
      int a0, b0, a1, b1;
      unpack_pair(k, a0, b0);
      if (b0 == 63) { a1 = a0 + 1; b1 = a1; } else { a1 = a0; b1 = b0 + 1; }
      float v0 = (a0 == b0) ? Ms[a0 * MS + a0] : (Ms[a0 * MS + b0] + Ms[b0 * MS + a0]);
      float v1 = (a1 == b1) ? Ms[a1 * MS + a1] : (Ms[a1 * MS + b1] + Ms[b1 * MS + a1]);
      *(uint16_t*)(row + k) = pk_fp8(v0, v1);
    }
    if (t < 32) *(uint16_t*)(row + KPACK + 2 * t) = pk_fp8(-us[2 * t], -us[2 * t + 1]);
    if (t >= 32 && t < 48) *(uint16_t*)(row + KCROSS + 2 * (t - 32)) = 0;
  }
}

// ---------------- GEMM (fp8): S_z[n,c] = sum_{k in slice z} Aq[n,k]*Bo[c,k] ---
// BM=64, BN=128, BK=128 fp8; z=2 (9/8 iters) -> 1024 blocks = 4 blocks/CU:
// 4 independent barrier groups per CU to overlap the staging drain.
// Grid = (64 rows FAST, 8 cols, 2 z) for XCD pinning. XOR 16B-chunk swizzle.
// MFMA operands SWAPPED (bf, af): D row = c, D col = n -> 8B packed stores.
#define BM 64
#define BN 128
#define BK 128
__global__ __launch_bounds__(256) void gemm_s(const uint8_t* __restrict__ Aq,
                                              const uint8_t* __restrict__ Bo,
                                              __bf16* __restrict__ Sbase) {
  __shared__ uint8_t As[BM * BK];   // 8 KB
  __shared__ uint8_t Bs[BN * BK];   // 16 KB
  int t = threadIdx.x;
  int lane = t & 63;
  int w = t >> 6;
  int wr = w & 1;                  // row half: rows [wr*32, +32)
  int wc = w >> 1;                 // col half: cols [wc*64, +64)
  int rowBase = blockIdx.x * BM;   // row index FASTEST for XCD pinning
  int colBase = blockIdx.y * BN;
  int kb = blockIdx.z ? KSPLIT : 0;
  int ke = blockIdx.z ? KTOT : KSPLIT;
  __bf16* S = Sbase + (size_t)blockIdx.z * ((size_t)N_ * CP);

  f32_4 acc[2][4];
  for (int mi = 0; mi < 2; ++mi)
    for (int ni = 0; ni < 4; ++ni)
      acc[mi][ni] = (f32_4){0.f, 0.f, 0.f, 0.f};

  int m0 = lane & 15;
  int q = lane >> 4;           // K-quarter within MFMA
  int sw = m0 & 7;             // swizzle key (row&7 == m0&7: 32,16 = 0 mod 8)

  for (int k0 = kb; k0 < ke; k0 += BK) {
    __syncthreads();
    // stage A: 64 rows x 8 chunks(16B) = 512 chunks, 2 rounds
    for (int r = 0; r < 2; ++r) {
      int ch = r * 256 + t;
      int row_p = ch >> 3, qp = ch & 7;
      int q_log = qp ^ (row_p & 7);
      const uint8_t* g = Aq + (size_t)(rowBase + row_p) * KTOT + k0 + (q_log << 4);
      gl2lds16(g, As + ch * 16);
    }
    // stage B: 128 rows x 8 chunks = 1024 chunks, 4 rounds
    for (int r = 0; r < 4; ++r) {
      int ch = r * 256 + t;
      int row_p = ch >> 3, qp = ch & 7;
      int q_log = qp ^ (row_p & 7);
      const uint8_t* g = Bo + (size_t)(colBase + row_p) * KTOT + k0 + (q_log << 4);
      gl2lds16(g, Bs + ch * 16);
    }
    __syncthreads();
    for (int s = 0; s < 4; ++s) {          // 4 x K=32 MFMA steps per BK=128
      int c_log = 2 * s + (q >> 1);        // logical 16B chunk of this lane's 8B
      int off = ((c_log ^ sw) << 4) + ((q & 1) << 3);
      long af[2], bf[4];
      for (int mi = 0; mi < 2; ++mi)
        af[mi] = *(const long*)&As[(wr * 32 + mi * 16 + m0) * BK + off];
      for (int ni = 0; ni < 4; ++ni)
        bf[ni] = *(const long*)&Bs[(wc * 64 + ni * 16 + m0) * BK + off];
      for (int mi = 0; mi < 2; ++mi)
        for (int ni = 0; ni < 4; ++ni)
          acc[mi][ni] = __builtin_amdgcn_mfma_f32_16x16x32_fp8_fp8(
              bf[ni], af[mi], acc[mi][ni], 0, 0, 0);   // SWAPPED operands
    }
  }

  // Swapped-D layout: row(=c) = (lane>>4)*4 + reg, col(=n) = lane&15.
  int ll = lane & 15;          // n offset
  int lh = lane >> 4;          // c quad
  for (int mi = 0; mi < 2; ++mi) {
    int n0 = rowBase + wr * 32 + mi * 16 + ll;
    for (int ni = 0; ni < 4; ++ni) {
      int c0 = colBase + wc * 64 + ni * 16 + lh * 4;
      union { __bf16 h[4]; uint2 u; } pk;
      for (int j = 0; j < 4; ++j) pk.h[j] = (__bf16)acc[mi][ni][j];
      *(uint2*)&S[(size_t)n0 * CP + c0] = pk.u;
    }
  }
}

// ---------------- epilogue: wave-per-row softmax + y passthrough ----------------
__global__ __launch_bounds__(256) void epilogue(
    const __bf16* __restrict__ Sb, const float* __restrict__ y,
    const float* __restrict__ w2, const float* __restrict__ qn,
    const int* __restrict__ tgt, const float* __restrict__ ratio_p,
    float* __restrict__ nll, float* __restrict__ outy) {
  int t = threadIdx.x, lane = t & 63, w = t >> 6;
  int n = blockIdx.x * 4 + w;
  float hr = 0.5f * (*ratio_p);
  int lbl = tgt[n];
  float q = qn[n];
  float w2k = w2[lbl];
  const bf16_8* S0 = (const bf16_8*)(Sb + (size_t)n * CP);
  const bf16_8* S1 = (const bf16_8*)(Sb + 1ull * N_ * CP + (size_t)n * CP);
  const float* yr = y + (size_t)n * C_;
  float* oy = outy + (size_t)n * C_;
  float l[16];
  float mx = -1e30f;
  for (int i = 0; i < 2; ++i) {
    int idx = i * 64 + lane;             // bf16_8 index; c = idx*8+j
    bf16_8 a0 = S0[idx], a1 = S1[idx];
    int c0 = idx * 8;
    for (int j = 0; j < 8; ++j) {
      int c = c0 + j;
      float v = -1e30f;
      if (c < C_) {
        float s = (float)a0[j] + (float)a1[j];
        v = yr[c] + (w2[c] - w2k) + hr * (s + q);
      }
      l[i * 8 + j] = v;
      mx = fmaxf(mx, v);
    }
  }
  // y passthrough (out+1 is only 4B-aligned -> scalar coalesced copy)
  for (int c = lane; c < C_; c += 64) oy[c] = yr[c];
  for (int o = 32; o; o >>= 1) mx = fmaxf(mx, __shfl_xor(mx, o));
  float se = 0.f, lt = 0.f;
  for (int i = 0; i < 2; ++i) {
    int c0 = (i * 64 + lane) * 8;
    for (int j = 0; j < 8; ++j) {
      float v = l[i * 8 + j];
      se += expf(v - mx);               // -1e30 lanes contribute exactly 0
      lt += (c0 + j == lbl) ? v : 0.f;
    }
  }
  for (int o = 32; o; o >>= 1) {
    se += __shfl_xor(se, o);
    lt += __shfl_xor(lt, o);
  }
  if (lane == 0) nll[n] = (mx + logf(se)) - lt;
}

// ---------------- final mean (single block, no atomics) ----------------
__global__ void reduce_loss(const float* __restrict__ nll, float* __restrict__ out) {
  int t = threadIdx.x;  // 256
  float s = 0.f;
  for (int i = t; i < N_; i += 256) s += nll[i];
  for (int o = 32; o; o >>= 1) s += __shfl_down(s, o);
  __shared__ float r[4];
  if ((t & 63) == 0) r[t >> 6] = s;
  __syncthreads();
  if (t == 0) out[0] = (r[0] + r[1] + r[2] + r[3]) * (1.0f / (float)N_);
}

extern "C" void kernel_launch(void* const* d_in, const int* in_sizes, int n_in,
                              void* d_out, int out_size, void* d_ws, size_t ws_size,
                              hipStream_t stream) {
  const float* W     = (const float*)d_in[0];   // (C, A)
  const float* y     = (const float*)d_in[1];   // (N, C)
  const int*   tgt   = (const int*)d_in[3];     // (N,)
  const float* ratio = (const float*)d_in[4];   // scalar
  const float* CV    = (const float*)d_in[5];   // (N, A, A)

  char* ws = (char*)d_ws;
  size_t off = 0;
  uint8_t* Aq = (uint8_t*)(ws + off); off += (size_t)N_ * KTOT;
  uint8_t* Bo = (uint8_t*)(ws + off); off += (size_t)CP * KTOT;
  __bf16* S   = (__bf16*)(ws + off);  off += 2ull * N_ * CP * sizeof(__bf16);
  float* w2   = (float*)(ws + off);   off += 4096;
  float* qn   = (float*)(ws + off);   off += (size_t)N_ * sizeof(float);
  float* nll  = (float*)(ws + off);   off += (size_t)N_ * sizeof(float);

  float* out = (float*)d_out;

  prep_all<<<1024 + N_, 256, 0, stream>>>(W, tgt, CV, Bo, w2, Aq, qn);
  gemm_s<<<dim3(N_ / BM, CP / BN, 2), 256, 0, stream>>>(Aq, Bo, S);
  epilogue<<<N_ / 4, 256, 0, stream>>>(S, y, w2, qn, tgt, ratio, nll, out + 1);
  reduce_loss<<<1, 256, 0, stream>>>(nll, out);
}